// Round 5
// baseline (14324.513 us; speedup 1.0000x reference)
//
#include <hip/hip_runtime.h>

// LSTM T=4096, I=512, H=2048, 4H=8192, O=1, fp32.
// R17 = R12 exact structure (verified best: 2 polling waves + hshare + B1,
// part[] + B2, wave-0 tail, NREP=4 coalesced publish) + packed xg + ONE
// isolated change: 2-deep staggered pipelined poll.
//  * prime batch A; s_sleep(7) (~450cy, sched_barrier-pinned); prime batch B;
//    then alternate check/reissue. Each check waits only its own batch
//    (partial vmcnt) -> sampling every ~L/2 instead of ~L.
//  * wave-1 s_sleep(8) backoff and in-loop s_sleep(1) dropped: with samples
//    continuously in flight, a failed sample no longer delays the next.
//  * R13-R16 lessons kept: publish stays 4 coalesced stores from t<8 (no
//    scatter), poll loop body branch-light (no per-word predication), no
//    butterfly tail, 2 pollers only.
// h published as tagged u64 (fp32bits<<32 | step), parity double buffer.

#define T_STEPS 4096
#define HID     2048
#define GATES   8192
#define KIN     512
#define NWG     256
#define NTHR    512
#define NREP    4
#define XG_BYTES ((size_t)T_STEPS * GATES * 4)
#define HCOM_BYTES ((size_t)NREP * 2 * HID * 8)   // 128 KB

typedef float v2f __attribute__((ext_vector_type(2)));

__device__ __forceinline__ float u2f(unsigned int u) {
    union { unsigned int u; float f; } x; x.u = u; return x.f;
}
__device__ __forceinline__ float fast_sigmoid(float x) {
    return 1.f / (1.f + __expf(-x));
}
__device__ __forceinline__ float fast_tanh(float x) {
    return 2.f / (1.f + __expf(-2.f * x)) - 1.f;
}

// ---------------- xg = X @ Wih^T + (bih+bhh), fp32 tiled, packed store ----
// Output layout: xgp[b][m][g*8+u] with b=(n>>3)&255, g=n>>11, u=n&7, so the
// 32 gate-values WG b needs at step m are 128B contiguous.
__global__ __launch_bounds__(256) void gemm_xg(const float* __restrict__ A,
                                               const float* __restrict__ B,
                                               const float* __restrict__ bih,
                                               const float* __restrict__ bhh,
                                               float* __restrict__ C) {
    __shared__ float As[32][68];
    __shared__ float Bs[32][68];
    const int t  = threadIdx.x;
    const int tx = t & 15, ty = t >> 4;
    const int m0 = blockIdx.y * 64, n0 = blockIdx.x * 64;
    const int sr = t >> 3, sc = (t & 7) * 4;

    float c[4][4] = {};
    for (int k0 = 0; k0 < KIN; k0 += 32) {
        float4 a0 = *(const float4*)(A + (size_t)(m0 + sr)      * KIN + k0 + sc);
        float4 a1 = *(const float4*)(A + (size_t)(m0 + sr + 32) * KIN + k0 + sc);
        float4 b0 = *(const float4*)(B + (size_t)(n0 + sr)      * KIN + k0 + sc);
        float4 b1 = *(const float4*)(B + (size_t)(n0 + sr + 32) * KIN + k0 + sc);
        __syncthreads();
        As[sc+0][sr] = a0.x; As[sc+1][sr] = a0.y; As[sc+2][sr] = a0.z; As[sc+3][sr] = a0.w;
        As[sc+0][sr+32] = a1.x; As[sc+1][sr+32] = a1.y; As[sc+2][sr+32] = a1.z; As[sc+3][sr+32] = a1.w;
        Bs[sc+0][sr] = b0.x; Bs[sc+1][sr] = b0.y; Bs[sc+2][sr] = b0.z; Bs[sc+3][sr] = b0.w;
        Bs[sc+0][sr+32] = b1.x; Bs[sc+1][sr+32] = b1.y; Bs[sc+2][sr+32] = b1.z; Bs[sc+3][sr+32] = b1.w;
        __syncthreads();
#pragma unroll
        for (int kk = 0; kk < 32; ++kk) {
            float4 av = *(const float4*)&As[kk][ty * 4];
            float4 bv = *(const float4*)&Bs[kk][tx * 4];
            c[0][0] = fmaf(av.x, bv.x, c[0][0]); c[0][1] = fmaf(av.x, bv.y, c[0][1]);
            c[0][2] = fmaf(av.x, bv.z, c[0][2]); c[0][3] = fmaf(av.x, bv.w, c[0][3]);
            c[1][0] = fmaf(av.y, bv.x, c[1][0]); c[1][1] = fmaf(av.y, bv.y, c[1][1]);
            c[1][2] = fmaf(av.y, bv.z, c[1][2]); c[1][3] = fmaf(av.y, bv.w, c[1][3]);
            c[2][0] = fmaf(av.z, bv.x, c[2][0]); c[2][1] = fmaf(av.z, bv.y, c[2][1]);
            c[2][2] = fmaf(av.z, bv.z, c[2][2]); c[2][3] = fmaf(av.z, bv.w, c[2][3]);
            c[3][0] = fmaf(av.w, bv.x, c[3][0]); c[3][1] = fmaf(av.w, bv.y, c[3][1]);
            c[3][2] = fmaf(av.w, bv.z, c[3][2]); c[3][3] = fmaf(av.w, bv.w, c[3][3]);
        }
    }
    const int col = n0 + tx * 4;
    float4 bias;
    bias.x = bih[col]   + bhh[col];
    bias.y = bih[col+1] + bhh[col+1];
    bias.z = bih[col+2] + bhh[col+2];
    bias.w = bih[col+3] + bhh[col+3];
    const int bb = (col >> 3) & (NWG - 1);
    const int gg = col >> 11;
    const int uu = col & 7;           // 0 or 4 -> float4 stays within one g-block
    float* dst = C + (size_t)bb * T_STEPS * 32 + gg * 8 + uu;
#pragma unroll
    for (int i = 0; i < 4; ++i) {
        float4 o;
        o.x = c[i][0] + bias.x; o.y = c[i][1] + bias.y;
        o.z = c[i][2] + bias.z; o.w = c[i][3] + bias.w;
        *(float4*)(dst + (size_t)(m0 + ty * 4 + i) * 32) = o;
    }
}

// ---------------- persistent recurrence ----------------
// 256 WGs x 512 thr. WG owns hidden [8b,8b+8) = 32 gate rows.
// kc=t&127 (k subset {g*128+kc}), rg=t>>7 gate group, 8 rows each.
// Waves 0-1 poll replica (wg&3) + rebroadcast via LDS; tail on wave 0.
// hcom layout: replica r, parity p at hcom + (r*2+p)*HID.
template<int USE_XG>
__global__ __launch_bounds__(NTHR, 2) void lstm_rec(
    const float* __restrict__ X,
    const float* __restrict__ Wih,
    const float* __restrict__ xg,
    const float* __restrict__ Whh,
    const float* __restrict__ bih,
    const float* __restrict__ bhh,
    unsigned long long* __restrict__ hcom)
{
    const int t  = threadIdx.x;
    const int kc = t & 127;
    const int rg = t >> 7;
    const int j0 = blockIdx.x * 8;
    const int rep = blockIdx.x & (NREP - 1);

    // register-resident W_hh slice, packed as float2 pairs over g
    v2f whh2[8][8];
#pragma unroll
    for (int m = 0; m < 8; ++m) {
        const float* wr = Whh + (size_t)(rg * HID + j0 + m) * HID + kc;
#pragma unroll
        for (int j = 0; j < 8; ++j) {
            v2f p; p.x = wr[(2 * j) * 128]; p.y = wr[(2 * j + 1) * 128];
            whh2[m][j] = p;
        }
    }
    float wih[8][4];
    if (!USE_XG) {
#pragma unroll
        for (int m = 0; m < 8; ++m) {
            float4 vx = *(const float4*)(Wih + (size_t)(rg * HID + j0 + m) * KIN + kc * 4);
            wih[m][0] = vx.x; wih[m][1] = vx.y; wih[m][2] = vx.z; wih[m][3] = vx.w;
        }
    }

    float brow = 0.f;
    if (t < 32) {
        const int grow = (t >> 3) * HID + j0 + (t & 7);
        brow = bih[grow] + bhh[grow];
    }

    __shared__ float hshare[HID];
    __shared__ float part[32 * 132];
    float c_state = 0.f;

    for (int s = 0; s < T_STEPS; ++s) {
        // prefetch xg (tail rows) before the poll — one 128B segment/WG/step
        float xgv = 0.f;
        if (USE_XG && t < 32)
            xgv = xg[((size_t)blockIdx.x * T_STEPS + s) * 32 + t];

        v2f hv2[8];
        if (t < 128) {
            // ---- 2-deep staggered pipelined poll (parity s&1) ----
            // Two 16-word sample batches ~L/2 apart stay in flight; each
            // check waits only on its own batch (partial vmcnt), so the
            // effective sampling period is ~half a load latency.
            const unsigned long long* hp = hcom + ((size_t)rep * 2 + (s & 1)) * HID;
            unsigned long long va[16], vb[16];
#pragma unroll
            for (int g = 0; g < 16; ++g)
                va[g] = __hip_atomic_load(hp + g * 128 + kc, __ATOMIC_RELAXED,
                                          __HIP_MEMORY_SCOPE_AGENT);
            __builtin_amdgcn_sched_barrier(0);
            __builtin_amdgcn_s_sleep(7);       // ~450cy half-round stagger
            __builtin_amdgcn_sched_barrier(0);
#pragma unroll
            for (int g = 0; g < 16; ++g)
                vb[g] = __hip_atomic_load(hp + g * 128 + kc, __ATOMIC_RELAXED,
                                          __HIP_MEMORY_SCOPE_AGENT);
            __builtin_amdgcn_sched_barrier(0);
            int guard = 1 << 17;
            for (;;) {
                bool okA = true;
#pragma unroll
                for (int g = 0; g < 16; ++g)
                    okA &= ((unsigned int)va[g] >= (unsigned int)s);
                if (okA) break;
                __builtin_amdgcn_sched_barrier(0);
#pragma unroll
                for (int g = 0; g < 16; ++g)
                    va[g] = __hip_atomic_load(hp + g * 128 + kc, __ATOMIC_RELAXED,
                                              __HIP_MEMORY_SCOPE_AGENT);
                __builtin_amdgcn_sched_barrier(0);
                bool okB = true;
#pragma unroll
                for (int g = 0; g < 16; ++g)
                    okB &= ((unsigned int)vb[g] >= (unsigned int)s);
                if (okB) {
#pragma unroll
                    for (int g = 0; g < 16; ++g) va[g] = vb[g];
                    break;
                }
                __builtin_amdgcn_sched_barrier(0);
#pragma unroll
                for (int g = 0; g < 16; ++g)
                    vb[g] = __hip_atomic_load(hp + g * 128 + kc, __ATOMIC_RELAXED,
                                              __HIP_MEMORY_SCOPE_AGENT);
                __builtin_amdgcn_sched_barrier(0);
                if (--guard <= 0) break;
            }
            // winner is in va; tags are monotone within the parity epoch, so
            // any sample with tag >= s holds the final h(s) value.
#pragma unroll
            for (int j = 0; j < 8; ++j) {
                v2f p;
                p.x = u2f((unsigned int)(va[2 * j] >> 32));
                p.y = u2f((unsigned int)(va[2 * j + 1] >> 32));
                hv2[j] = p;
                hshare[(2 * j) * 128 + kc]     = p.x;
                hshare[(2 * j + 1) * 128 + kc] = p.y;
            }
        }
        __syncthreads();                     // B1: hshare ready
        if (t >= 128) {
#pragma unroll
            for (int j = 0; j < 8; ++j) {
                v2f p;
                p.x = hshare[(2 * j) * 128 + kc];
                p.y = hshare[(2 * j + 1) * 128 + kc];
                hv2[j] = p;
            }
        }

        v2f acc2[8];
        if (!USE_XG) {
            float4 x4 = *(const float4*)(X + (size_t)s * KIN + kc * 4);
#pragma unroll
            for (int m = 0; m < 8; ++m) {
                float a = wih[m][0] * x4.x;
                a = fmaf(wih[m][1], x4.y, a);
                a = fmaf(wih[m][2], x4.z, a);
                a = fmaf(wih[m][3], x4.w, a);
                v2f z; z.x = a; z.y = 0.f; acc2[m] = z;
            }
        } else {
#pragma unroll
            for (int m = 0; m < 8; ++m) { v2f z; z.x = 0.f; z.y = 0.f; acc2[m] = z; }
        }

        // packed dot: 64 v_pk_fma_f32 per thread
#pragma unroll
        for (int m = 0; m < 8; ++m) {
            v2f a = acc2[m];
#pragma unroll
            for (int j = 0; j < 8; ++j)
                a = __builtin_elementwise_fma(whh2[m][j], hv2[j], a);
            acc2[m] = a;
        }
#pragma unroll
        for (int m = 0; m < 8; ++m)
            part[(rg * 8 + m) * 132 + kc] = acc2[m].x + acc2[m].y;
        __syncthreads();                     // B2: partials ready

        // tail: 64 threads reduce (2 per row), shuffle combine, 8 threads gate
        if (t < 64) {
            const int row = t & 31, half = t >> 5;
            const float4* p4 = (const float4*)(part + row * 132 + half * 64);
            float s0 = 0.f, s1 = 0.f, s2 = 0.f, s3 = 0.f;
#pragma unroll
            for (int i = 0; i < 16; ++i) {
                float4 pv = p4[i];
                s0 += pv.x; s1 += pv.y; s2 += pv.z; s3 += pv.w;
            }
            float sum = (s0 + s1) + (s2 + s3);
            sum += __shfl_xor(sum, 32, 64);  // combine the two halves
            sum += brow + xgv;               // valid on t<32 (rows)
            const float a1 = __shfl_down(sum, 8, 64);
            const float a2 = __shfl_down(sum, 16, 64);
            const float a3 = __shfl_down(sum, 24, 64);
            if (t < 8) {
                const float i_s = fast_sigmoid(sum);   // gate i (row t)
                const float f_s = fast_sigmoid(a1);    // gate f (row 8+t)
                const float g_t = fast_tanh(a2);       // gate g (row 16+t)
                const float o_s = fast_sigmoid(a3);    // gate o (row 24+t)
                c_state = f_s * c_state + i_s * g_t;
                const float h = o_s * fast_tanh(c_state);
                const unsigned long long pk =
                    ((unsigned long long)__float_as_uint(h) << 32) | (unsigned int)(s + 1);
                const size_t slot = (size_t)((s + 1) & 1) * HID + j0 + t;
#pragma unroll
                for (int r = 0; r < NREP; ++r)
                    __hip_atomic_store(&hcom[(size_t)r * 2 * HID + slot], pk,
                                       __ATOMIC_RELAXED, __HIP_MEMORY_SCOPE_AGENT);
            }
        }
        // reuse safety (per replica): overwriting parity-p slot s with s+2
        // requires THIS WG to pass poll(s+1), which requires every WG
        // (incl. any reader still at step s) to have published s+1 — which
        // they only do after finishing step s. Same invariant as R11/R12.
    }
}

// ---------------- out[0] = h_T . W_lin + b_lin ----------------
__global__ __launch_bounds__(256) void final_linear(const unsigned long long* __restrict__ hcom,
                                                    const float* __restrict__ Wlin,
                                                    const float* __restrict__ blin,
                                                    float* __restrict__ out) {
    __shared__ float red[4];
    const int t = threadIdx.x;
    float a = 0.f;
#pragma unroll
    for (int e = 0; e < 8; ++e) {
        const int idx = t * 8 + e;   // replica 0, parity 0 holds h_T (tag 4096)
        a = fmaf(Wlin[idx], u2f((unsigned int)(hcom[idx] >> 32)), a);
    }
#pragma unroll
    for (int m = 1; m < 64; m <<= 1) a += __shfl_xor(a, m, 64);
    if ((t & 63) == 0) red[t >> 6] = a;
    __syncthreads();
    if (t == 0) out[0] = red[0] + red[1] + red[2] + red[3] + blin[0];
}

extern "C" void kernel_launch(void* const* d_in, const int* in_sizes, int n_in,
                              void* d_out, int out_size, void* d_ws, size_t ws_size,
                              hipStream_t stream) {
    const float* X    = (const float*)d_in[0];
    const float* Wih  = (const float*)d_in[1];
    const float* Whh  = (const float*)d_in[2];
    const float* bih  = (const float*)d_in[3];
    const float* bhh  = (const float*)d_in[4];
    const float* Wlin = (const float*)d_in[5];
    const float* blin = (const float*)d_in[6];
    float* out = (float*)d_out;

    char* ws = (char*)d_ws;
    const bool big = ws_size >= XG_BYTES + HCOM_BYTES;

    if (big) {
        float* xg = (float*)ws;
        unsigned long long* hcom = (unsigned long long*)(ws + XG_BYTES);
        (void)hipMemsetAsync(hcom, 0, HCOM_BYTES, stream);
        gemm_xg<<<dim3(GATES / 64, T_STEPS / 64), 256, 0, stream>>>(X, Wih, bih, bhh, xg);
        lstm_rec<1><<<dim3(NWG), dim3(NTHR), 0, stream>>>(X, Wih, xg, Whh, bih, bhh, hcom);
        final_linear<<<1, 256, 0, stream>>>(hcom, Wlin, blin, out);
    } else {
        unsigned long long* hcom = (unsigned long long*)ws;
        (void)hipMemsetAsync(hcom, 0, HCOM_BYTES, stream);
        lstm_rec<0><<<dim3(NWG), dim3(NTHR), 0, stream>>>(X, Wih, nullptr, Whh, bih, bhh, hcom);
        final_linear<<<1, 256, 0, stream>>>(hcom, Wlin, blin, out);
    }
}

// Round 6
// 10213.037 us; speedup vs baseline: 1.4026x; 1.4026x over previous
//
#include <hip/hip_runtime.h>

// LSTM T=4096, I=512, H=2048, 4H=8192, O=1, fp32.
// R18 = lstm_rec/final_linear/launch restored BIT-EXACT from R12 (verified
// best, 10.18ms lstm) after 5 consecutive structural regressions
// (R13 scatter-publish, R14 predicated poll, R15 butterfly tail,
// R16 all-waves-poll, R17 pipelined poll). The ONLY change this round is
// gemm_xg: fp32 VALU tiles -> split-bf16 3-term MFMA (hi*hi + hi*lo + lo*hi,
// ~2^-17 rel err, fp32-class accuracy), same unpacked output layout.
// h published as tagged u64 (fp32bits<<32 | step), parity double buffer.

#define T_STEPS 4096
#define HID     2048
#define GATES   8192
#define KIN     512
#define NWG     256
#define NTHR    512
#define NREP    4
#define XG_BYTES ((size_t)T_STEPS * GATES * 4)
#define HCOM_BYTES ((size_t)NREP * 2 * HID * 8)   // 128 KB

typedef float v2f __attribute__((ext_vector_type(2)));
typedef __attribute__((ext_vector_type(8))) short bf16x8;   // 8 bf16 (4 VGPRs)
typedef __attribute__((ext_vector_type(4))) float f32x4a;   // MFMA acc

__device__ __forceinline__ float u2f(unsigned int u) {
    union { unsigned int u; float f; } x; x.u = u; return x.f;
}
__device__ __forceinline__ float fast_sigmoid(float x) {
    return 1.f / (1.f + __expf(-x));
}
__device__ __forceinline__ float fast_tanh(float x) {
    return 2.f / (1.f + __expf(-2.f * x)) - 1.f;
}
__device__ __forceinline__ unsigned short f2bf(float f) {   // RNE f32->bf16
    unsigned int u = __float_as_uint(f);
    unsigned int r = u + 0x7FFFu + ((u >> 16) & 1u);
    return (unsigned short)(r >> 16);
}
__device__ __forceinline__ float bf2f(unsigned short h) {
    return __uint_as_float(((unsigned int)h) << 16);
}

// ---------------- xg = X @ Wih^T + (bih+bhh), split-bf16 MFMA ----------------
// C[m][n] = sum_k X[m][k] * Wih[n][k]  (B^T gemm: both inputs K-contiguous).
// 64x64 tile, 4 waves, wave (wm,wn) owns a 32x32 quadrant = 2x2 frags of
// 16x16x32_bf16. Split each f32 v into hi=bf16(v), lo=bf16(v-hi); accumulate
// hi*hi + hi*lo + lo*hi (drop lo*lo ~2^-34). Fragment maps (guide-verified):
//   A: row=lane&15, k=(lane>>4)*8+i    B: col=lane&15, k=(lane>>4)*8+i
//   C: col=lane&15, row=(lane>>4)*4+reg   (m89)
// LDS pitch 40 bf16 (80B rows): frag b128 reads land 2 lanes/bank (free).
__global__ __launch_bounds__(256) void gemm_xg(const float* __restrict__ A,
                                               const float* __restrict__ B,
                                               const float* __restrict__ bih,
                                               const float* __restrict__ bhh,
                                               float* __restrict__ C) {
    __shared__ unsigned short Ah[64][40], Al[64][40];
    __shared__ unsigned short Bh[64][40], Bl[64][40];
    const int t  = threadIdx.x;
    const int l  = t & 63;
    const int w  = t >> 6;
    const int wm = w >> 1, wn = w & 1;
    const int m0 = blockIdx.y * 64, n0 = blockIdx.x * 64;
    const int sr = t >> 3;          // 0..31 (stage row; +32 for second half)
    const int sc = (t & 7) * 4;     // 0..28 (stage col, 4 floats)
    const int lr = l & 15;          // frag row/col within 16
    const int kq = (l >> 4) * 8;    // frag k-offset

    f32x4a acc[2][2] = {};

    for (int k0 = 0; k0 < KIN; k0 += 32) {
        float4 a0 = *(const float4*)(A + (size_t)(m0 + sr)      * KIN + k0 + sc);
        float4 a1 = *(const float4*)(A + (size_t)(m0 + sr + 32) * KIN + k0 + sc);
        float4 b0 = *(const float4*)(B + (size_t)(n0 + sr)      * KIN + k0 + sc);
        float4 b1 = *(const float4*)(B + (size_t)(n0 + sr + 32) * KIN + k0 + sc);
        __syncthreads();            // protect previous iter's frag reads
        {
            ushort4 h, lo;
            h.x = f2bf(a0.x); lo.x = f2bf(a0.x - bf2f(h.x));
            h.y = f2bf(a0.y); lo.y = f2bf(a0.y - bf2f(h.y));
            h.z = f2bf(a0.z); lo.z = f2bf(a0.z - bf2f(h.z));
            h.w = f2bf(a0.w); lo.w = f2bf(a0.w - bf2f(h.w));
            *(ushort4*)&Ah[sr][sc] = h; *(ushort4*)&Al[sr][sc] = lo;
            h.x = f2bf(a1.x); lo.x = f2bf(a1.x - bf2f(h.x));
            h.y = f2bf(a1.y); lo.y = f2bf(a1.y - bf2f(h.y));
            h.z = f2bf(a1.z); lo.z = f2bf(a1.z - bf2f(h.z));
            h.w = f2bf(a1.w); lo.w = f2bf(a1.w - bf2f(h.w));
            *(ushort4*)&Ah[sr + 32][sc] = h; *(ushort4*)&Al[sr + 32][sc] = lo;
            h.x = f2bf(b0.x); lo.x = f2bf(b0.x - bf2f(h.x));
            h.y = f2bf(b0.y); lo.y = f2bf(b0.y - bf2f(h.y));
            h.z = f2bf(b0.z); lo.z = f2bf(b0.z - bf2f(h.z));
            h.w = f2bf(b0.w); lo.w = f2bf(b0.w - bf2f(h.w));
            *(ushort4*)&Bh[sr][sc] = h; *(ushort4*)&Bl[sr][sc] = lo;
            h.x = f2bf(b1.x); lo.x = f2bf(b1.x - bf2f(h.x));
            h.y = f2bf(b1.y); lo.y = f2bf(b1.y - bf2f(h.y));
            h.z = f2bf(b1.z); lo.z = f2bf(b1.z - bf2f(h.z));
            h.w = f2bf(b1.w); lo.w = f2bf(b1.w - bf2f(h.w));
            *(ushort4*)&Bh[sr + 32][sc] = h; *(ushort4*)&Bl[sr + 32][sc] = lo;
        }
        __syncthreads();            // tiles ready

        bf16x8 ah[2], al2[2], bh2[2], bl2[2];
#pragma unroll
        for (int fr = 0; fr < 2; ++fr) {
            const int ar = wm * 32 + fr * 16 + lr;
            ah[fr]  = *(const bf16x8*)&Ah[ar][kq];
            al2[fr] = *(const bf16x8*)&Al[ar][kq];
            const int br = wn * 32 + fr * 16 + lr;
            bh2[fr] = *(const bf16x8*)&Bh[br][kq];
            bl2[fr] = *(const bf16x8*)&Bl[br][kq];
        }
#pragma unroll
        for (int fr = 0; fr < 2; ++fr)
#pragma unroll
            for (int fc = 0; fc < 2; ++fc) {
                acc[fr][fc] = __builtin_amdgcn_mfma_f32_16x16x32_bf16(
                    ah[fr], bh2[fc], acc[fr][fc], 0, 0, 0);
                acc[fr][fc] = __builtin_amdgcn_mfma_f32_16x16x32_bf16(
                    ah[fr], bl2[fc], acc[fr][fc], 0, 0, 0);
                acc[fr][fc] = __builtin_amdgcn_mfma_f32_16x16x32_bf16(
                    al2[fr], bh2[fc], acc[fr][fc], 0, 0, 0);
            }
    }

    // epilogue: bias + unpacked store (same layout R12's lstm reads)
#pragma unroll
    for (int fc = 0; fc < 2; ++fc) {
        const int col = n0 + wn * 32 + fc * 16 + lr;
        const float bs = bih[col] + bhh[col];
#pragma unroll
        for (int fr = 0; fr < 2; ++fr) {
            const int rowb = m0 + wm * 32 + fr * 16 + (l >> 4) * 4;
#pragma unroll
            for (int j = 0; j < 4; ++j)
                C[(size_t)(rowb + j) * GATES + col] = acc[fr][fc][j] + bs;
        }
    }
}

// ---------------- persistent recurrence (R12 verbatim) ----------------
// 256 WGs x 512 thr. WG owns hidden [8b,8b+8) = 32 gate rows.
// kc=t&127 (k subset {g*128+kc}), rg=t>>7 gate group, 8 rows each.
// Waves 0-1 poll replica (wg&3) + rebroadcast via LDS; tail on wave 0.
// hcom layout: replica r, parity p at hcom + (r*2+p)*HID.
template<int USE_XG>
__global__ __launch_bounds__(NTHR, 2) void lstm_rec(
    const float* __restrict__ X,
    const float* __restrict__ Wih,
    const float* __restrict__ xg,
    const float* __restrict__ Whh,
    const float* __restrict__ bih,
    const float* __restrict__ bhh,
    unsigned long long* __restrict__ hcom)
{
    const int t  = threadIdx.x;
    const int kc = t & 127;
    const int rg = t >> 7;
    const int j0 = blockIdx.x * 8;
    const int rep = blockIdx.x & (NREP - 1);

    // register-resident W_hh slice, packed as float2 pairs over g
    v2f whh2[8][8];
#pragma unroll
    for (int m = 0; m < 8; ++m) {
        const float* wr = Whh + (size_t)(rg * HID + j0 + m) * HID + kc;
#pragma unroll
        for (int j = 0; j < 8; ++j) {
            v2f p; p.x = wr[(2 * j) * 128]; p.y = wr[(2 * j + 1) * 128];
            whh2[m][j] = p;
        }
    }
    float wih[8][4];
    if (!USE_XG) {
#pragma unroll
        for (int m = 0; m < 8; ++m) {
            float4 vx = *(const float4*)(Wih + (size_t)(rg * HID + j0 + m) * KIN + kc * 4);
            wih[m][0] = vx.x; wih[m][1] = vx.y; wih[m][2] = vx.z; wih[m][3] = vx.w;
        }
    }

    float brow = 0.f;
    if (t < 32) {
        const int grow = (t >> 3) * HID + j0 + (t & 7);
        brow = bih[grow] + bhh[grow];
    }

    __shared__ float hshare[HID];
    __shared__ float part[32 * 132];
    float c_state = 0.f;

    for (int s = 0; s < T_STEPS; ++s) {
        // prefetch xg (reducer rows) before the poll — hides HBM/LLC latency
        float xgv = 0.f;
        if (USE_XG && t < 32)
            xgv = xg[(size_t)s * GATES + (t >> 3) * HID + j0 + (t & 7)];

        v2f hv2[8];
        if (t < 128) {
            // Wave 1 delays its first round past the publish window; wave 0's
            // tail provides that delay naturally. (R11 lesson.)
            if (t >= 64 && s > 0) __builtin_amdgcn_s_sleep(8);
            // poll my replica's 16 tagged words (parity s&1)
            const unsigned long long* hp = hcom + ((size_t)rep * 2 + (s & 1)) * HID;
            unsigned long long v[16];
            int guard = 1 << 18;
            for (;;) {
#pragma unroll
                for (int g = 0; g < 16; ++g)
                    v[g] = __hip_atomic_load(hp + g * 128 + kc, __ATOMIC_RELAXED,
                                             __HIP_MEMORY_SCOPE_AGENT);
                bool ok = true;
#pragma unroll
                for (int g = 0; g < 16; ++g)
                    ok &= ((unsigned int)v[g] >= (unsigned int)s);
                if (ok || --guard <= 0) break;
                __builtin_amdgcn_s_sleep(1);   // rate-limit the poll storm
            }
#pragma unroll
            for (int j = 0; j < 8; ++j) {
                v2f p;
                p.x = u2f((unsigned int)(v[2 * j] >> 32));
                p.y = u2f((unsigned int)(v[2 * j + 1] >> 32));
                hv2[j] = p;
                hshare[(2 * j) * 128 + kc]     = p.x;
                hshare[(2 * j + 1) * 128 + kc] = p.y;
            }
        }
        __syncthreads();                     // B1: hshare ready
        if (t >= 128) {
#pragma unroll
            for (int j = 0; j < 8; ++j) {
                v2f p;
                p.x = hshare[(2 * j) * 128 + kc];
                p.y = hshare[(2 * j + 1) * 128 + kc];
                hv2[j] = p;
            }
        }

        v2f acc2[8];
        if (!USE_XG) {
            float4 x4 = *(const float4*)(X + (size_t)s * KIN + kc * 4);
#pragma unroll
            for (int m = 0; m < 8; ++m) {
                float a = wih[m][0] * x4.x;
                a = fmaf(wih[m][1], x4.y, a);
                a = fmaf(wih[m][2], x4.z, a);
                a = fmaf(wih[m][3], x4.w, a);
                v2f z; z.x = a; z.y = 0.f; acc2[m] = z;
            }
        } else {
#pragma unroll
            for (int m = 0; m < 8; ++m) { v2f z; z.x = 0.f; z.y = 0.f; acc2[m] = z; }
        }

        // packed dot: 64 v_pk_fma_f32 per thread
#pragma unroll
        for (int m = 0; m < 8; ++m) {
            v2f a = acc2[m];
#pragma unroll
            for (int j = 0; j < 8; ++j)
                a = __builtin_elementwise_fma(whh2[m][j], hv2[j], a);
            acc2[m] = a;
        }
#pragma unroll
        for (int m = 0; m < 8; ++m)
            part[(rg * 8 + m) * 132 + kc] = acc2[m].x + acc2[m].y;
        __syncthreads();                     // B2: partials ready

        // tail: 64 threads reduce (2 per row), shuffle combine, 8 threads gate
        if (t < 64) {
            const int row = t & 31, half = t >> 5;
            const float4* p4 = (const float4*)(part + row * 132 + half * 64);
            float s0 = 0.f, s1 = 0.f, s2 = 0.f, s3 = 0.f;
#pragma unroll
            for (int i = 0; i < 16; ++i) {
                float4 pv = p4[i];
                s0 += pv.x; s1 += pv.y; s2 += pv.z; s3 += pv.w;
            }
            float sum = (s0 + s1) + (s2 + s3);
            sum += __shfl_xor(sum, 32, 64);  // combine the two halves
            sum += brow + xgv;               // valid on t<32 (rows)
            const float a1 = __shfl_down(sum, 8, 64);
            const float a2 = __shfl_down(sum, 16, 64);
            const float a3 = __shfl_down(sum, 24, 64);
            if (t < 8) {
                const float i_s = fast_sigmoid(sum);   // gate i (row t)
                const float f_s = fast_sigmoid(a1);    // gate f (row 8+t)
                const float g_t = fast_tanh(a2);       // gate g (row 16+t)
                const float o_s = fast_sigmoid(a3);    // gate o (row 24+t)
                c_state = f_s * c_state + i_s * g_t;
                const float h = o_s * fast_tanh(c_state);
                const unsigned long long pk =
                    ((unsigned long long)__float_as_uint(h) << 32) | (unsigned int)(s + 1);
                const size_t slot = (size_t)((s + 1) & 1) * HID + j0 + t;
#pragma unroll
                for (int r = 0; r < NREP; ++r)
                    __hip_atomic_store(&hcom[(size_t)r * 2 * HID + slot], pk,
                                       __ATOMIC_RELAXED, __HIP_MEMORY_SCOPE_AGENT);
            }
        }
        // reuse safety (per replica): overwriting parity-p slot s with s+2
        // requires THIS WG to pass poll(s+1), which requires every WG
        // (incl. any reader still at step s) to have published s+1 — which
        // they only do after finishing step s. Same invariant as R11.
    }
}

// ---------------- out[0] = h_T . W_lin + b_lin ----------------
__global__ __launch_bounds__(256) void final_linear(const unsigned long long* __restrict__ hcom,
                                                    const float* __restrict__ Wlin,
                                                    const float* __restrict__ blin,
                                                    float* __restrict__ out) {
    __shared__ float red[4];
    const int t = threadIdx.x;
    float a = 0.f;
#pragma unroll
    for (int e = 0; e < 8; ++e) {
        const int idx = t * 8 + e;   // replica 0, parity 0 holds h_T (tag 4096)
        a = fmaf(Wlin[idx], u2f((unsigned int)(hcom[idx] >> 32)), a);
    }
#pragma unroll
    for (int m = 1; m < 64; m <<= 1) a += __shfl_xor(a, m, 64);
    if ((t & 63) == 0) red[t >> 6] = a;
    __syncthreads();
    if (t == 0) out[0] = red[0] + red[1] + red[2] + red[3] + blin[0];
}

extern "C" void kernel_launch(void* const* d_in, const int* in_sizes, int n_in,
                              void* d_out, int out_size, void* d_ws, size_t ws_size,
                              hipStream_t stream) {
    const float* X    = (const float*)d_in[0];
    const float* Wih  = (const float*)d_in[1];
    const float* Whh  = (const float*)d_in[2];
    const float* bih  = (const float*)d_in[3];
    const float* bhh  = (const float*)d_in[4];
    const float* Wlin = (const float*)d_in[5];
    const float* blin = (const float*)d_in[6];
    float* out = (float*)d_out;

    char* ws = (char*)d_ws;
    const bool big = ws_size >= XG_BYTES + HCOM_BYTES;

    if (big) {
        float* xg = (float*)ws;
        unsigned long long* hcom = (unsigned long long*)(ws + XG_BYTES);
        (void)hipMemsetAsync(hcom, 0, HCOM_BYTES, stream);
        gemm_xg<<<dim3(GATES / 64, T_STEPS / 64), 256, 0, stream>>>(X, Wih, bih, bhh, xg);
        lstm_rec<1><<<dim3(NWG), dim3(NTHR), 0, stream>>>(X, Wih, xg, Whh, bih, bhh, hcom);
        final_linear<<<1, 256, 0, stream>>>(hcom, Wlin, blin, out);
    } else {
        unsigned long long* hcom = (unsigned long long*)ws;
        (void)hipMemsetAsync(hcom, 0, HCOM_BYTES, stream);
        lstm_rec<0><<<dim3(NWG), dim3(NTHR), 0, stream>>>(X, Wih, nullptr, Whh, bih, bhh, hcom);
        final_linear<<<1, 256, 0, stream>>>(hcom, Wlin, blin, out);
    }
}